// Round 4
// baseline (380.020 us; speedup 1.0000x reference)
//
#include <hip/hip_runtime.h>

#define DIM 64
#define BN_EPS 1e-5f
#define L2_EPS 1e-12f

// ---------- build CSR by dst ----------
__global__ __launch_bounds__(256) void k_hist(const int* __restrict__ ei,
                                              int* __restrict__ cnt, int E) {
    int e = blockIdx.x * blockDim.x + threadIdx.x;
    if (e < E) atomicAdd(&cnt[ei[E + e]], 1);
}

// single-block exclusive scan over cnt -> offs/cur, plus dinv = rsqrt(cnt+1)
__global__ __launch_bounds__(1024) void k_scan(const int* __restrict__ cnt,
                                               int* __restrict__ offs,
                                               int* __restrict__ cur,
                                               float* __restrict__ dinv, int N, int E) {
    __shared__ int part[1024];
    int t = threadIdx.x;
    int per = (N + 1023) / 1024;
    int lo = t * per, hi = min(lo + per, N);
    int s = 0;
    for (int i = lo; i < hi; ++i) s += cnt[i];
    part[t] = s;
    __syncthreads();
    for (int off = 1; off < 1024; off <<= 1) {
        int v = (t >= off) ? part[t - off] : 0;
        __syncthreads();
        part[t] += v;
        __syncthreads();
    }
    int run = part[t] - s;   // exclusive prefix of this thread's range
    for (int i = lo; i < hi; ++i) {
        int c = cnt[i];
        offs[i] = run;
        cur[i] = run;
        dinv[i] = rsqrtf((float)(c + 1));
        run += c;
    }
    if (t == 0) offs[N] = E;
}

__global__ __launch_bounds__(256) void k_reorder(const int* __restrict__ ei,
                                                 int* __restrict__ cur,
                                                 int* __restrict__ es, int E) {
    int e = blockIdx.x * blockDim.x + threadIdx.x;
    if (e < E) {
        int s = ei[e];
        int d = ei[E + e];
        int p = atomicAdd(&cur[d], 1);
        es[p] = s;
    }
}

// ---------- h = x @ W ; out = h*dinv^2 + b (self-loop + bias) ----------
__global__ __launch_bounds__(256) void k_gemm(const float* __restrict__ x,
                                              const float* __restrict__ W,
                                              const float* __restrict__ b,
                                              const float* __restrict__ dinv,
                                              float* __restrict__ h,
                                              float* __restrict__ out, int N) {
    __shared__ float Ws[DIM][DIM];
    __shared__ float xs[4][DIM];
    int tid = threadIdx.x;
    for (int i = tid; i < DIM * DIM; i += 256) Ws[i >> 6][i & 63] = W[i];
    __syncthreads();
    int tx = tid & 63, ty = tid >> 6;
    float bj = b[tx];
    for (int r0 = blockIdx.x * 4; r0 < N; r0 += gridDim.x * 4) {
        int r = r0 + ty;
        __syncthreads();
        xs[ty][tx] = x[r * DIM + tx];
        __syncthreads();
        float acc = 0.f;
#pragma unroll
        for (int k = 0; k < DIM; ++k) acc = fmaf(xs[ty][k], Ws[k][tx], acc);
        h[r * DIM + tx] = acc;
        float di = dinv[r];
        out[r * DIM + tx] = acc * di * di + bj;
    }
}

// ---------- gather: one wave per dst row; 4 edges x 16 lanes x float4 ----------
__global__ __launch_bounds__(256) void k_gather(const int* __restrict__ offs,
                                                const int* __restrict__ es,
                                                const float* __restrict__ dinv,
                                                const float* __restrict__ h,
                                                float* __restrict__ out, int N) {
    int w = threadIdx.x >> 6;             // wave in block (0..3)
    int d = blockIdx.x * 4 + w;           // dst node
    if (d >= N) return;
    int l = threadIdx.x & 63;
    int sub = l >> 4;                     // edge slot 0..3
    int c = l & 15;                       // float4 column
    int beg = offs[d], end = offs[d + 1];
    const float4* __restrict__ h4 = (const float4*)h;
    float4 acc = make_float4(0.f, 0.f, 0.f, 0.f);
    for (int base = beg; base < end; base += 4) {
        int k = base + sub;
        bool valid = k < end;
        int idx = valid ? k : beg;
        int s = es[idx];
        float wgt = valid ? dinv[s] : 0.f;
        float4 hv = h4[(size_t)s * 16 + c];
        acc.x = fmaf(wgt, hv.x, acc.x);
        acc.y = fmaf(wgt, hv.y, acc.y);
        acc.z = fmaf(wgt, hv.z, acc.z);
        acc.w = fmaf(wgt, hv.w, acc.w);
    }
    // fold the 4 edge groups: lanes differ only in `sub`
    acc.x += __shfl_xor(acc.x, 16, 64); acc.y += __shfl_xor(acc.y, 16, 64);
    acc.z += __shfl_xor(acc.z, 16, 64); acc.w += __shfl_xor(acc.w, 16, 64);
    acc.x += __shfl_xor(acc.x, 32, 64); acc.y += __shfl_xor(acc.y, 32, 64);
    acc.z += __shfl_xor(acc.z, 32, 64); acc.w += __shfl_xor(acc.w, 32, 64);
    if (sub == 0) {
        float dd = dinv[d];
        float4* out4 = (float4*)out;
        float4 o = out4[(size_t)d * 16 + c];
        o.x = fmaf(dd, acc.x, o.x);
        o.y = fmaf(dd, acc.y, o.y);
        o.z = fmaf(dd, acc.z, o.z);
        o.w = fmaf(dd, acc.w, o.w);
        out4[(size_t)d * 16 + c] = o;
    }
}

// ---------- column stats ----------
__global__ __launch_bounds__(256) void k_stats(const float* __restrict__ out,
                                               float* __restrict__ stats, int N) {
    int tx = threadIdx.x & 63, ty = threadIdx.x >> 6;
    float s = 0.f, q = 0.f;
    for (int r = blockIdx.x * 4 + ty; r < N; r += gridDim.x * 4) {
        float v = out[r * DIM + tx];
        s += v;
        q = fmaf(v, v, q);
    }
    __shared__ float ls[4][DIM], lq[4][DIM];
    ls[ty][tx] = s;
    lq[ty][tx] = q;
    __syncthreads();
    if (ty == 0) {
        s = ls[0][tx] + ls[1][tx] + ls[2][tx] + ls[3][tx];
        q = lq[0][tx] + lq[1][tx] + lq[2][tx] + lq[3][tx];
        atomicAdd(&stats[tx], s);
        atomicAdd(&stats[DIM + tx], q);
    }
}

// ---------- BN -> ReLU -> row L2 normalize ----------
__global__ __launch_bounds__(256) void k_final(float* __restrict__ out,
                                               const float* __restrict__ stats,
                                               const float* __restrict__ gamma,
                                               const float* __restrict__ beta,
                                               int N, float invN) {
    int tx = threadIdx.x & 63;
    int r = (blockIdx.x * blockDim.x + threadIdx.x) >> 6;
    if (r >= N) return;
    float mean = stats[tx] * invN;
    float var = fmaf(-mean, mean, stats[DIM + tx] * invN);
    float rstd = rsqrtf(var + BN_EPS);
    float v = out[r * DIM + tx];
    v = (v - mean) * rstd * gamma[tx] + beta[tx];
    v = fmaxf(v, 0.f);
    float q = v * v;
#pragma unroll
    for (int off = 32; off; off >>= 1) q += __shfl_xor(q, off, 64);
    float nrm = sqrtf(q);
    out[r * DIM + tx] = v / fmaxf(nrm, L2_EPS);
}

extern "C" void kernel_launch(void* const* d_in, const int* in_sizes, int n_in,
                              void* d_out, int out_size, void* d_ws, size_t ws_size,
                              hipStream_t stream) {
    const float* x     = (const float*)d_in[0];
    const int*   ei    = (const int*)d_in[1];
    const float* W     = (const float*)d_in[2];
    const float* b     = (const float*)d_in[3];
    const float* gamma = (const float*)d_in[4];
    const float* beta  = (const float*)d_in[5];
    float* out = (float*)d_out;

    const int N = in_sizes[0] / DIM;      // 50000
    const int E = in_sizes[1] / 2;        // 800000

    // workspace layout (element offsets, padded to 256-elem boundaries)
    float* wsf = (float*)d_ws;
    const int STATS_OFF = 0;                                   // 128 f
    const int CNT_OFF   = 256;                                 // N int
    const int OFFS_OFF  = CNT_OFF  + ((N + 256) & ~255);       // N+1 int
    const int CUR_OFF   = OFFS_OFF + ((N + 256) & ~255);       // N int
    const int DINV_OFF  = CUR_OFF  + ((N + 256) & ~255);       // N f
    const int H_OFF     = DINV_OFF + ((N + 256) & ~255);       // N*64 f (16B aligned)
    const int ES_OFF    = H_OFF + N * DIM;                     // E int

    float* stats = wsf + STATS_OFF;
    int*   cnt   = (int*)(wsf + CNT_OFF);
    int*   offs  = (int*)(wsf + OFFS_OFF);
    int*   cur   = (int*)(wsf + CUR_OFF);
    float* dinv  = wsf + DINV_OFF;
    float* h     = wsf + H_OFF;
    int*   es    = (int*)(wsf + ES_OFF);

    // zero stats + cnt in one shot (contiguous region)
    hipMemsetAsync(wsf, 0, (size_t)(CNT_OFF + N) * sizeof(float), stream);

    k_hist   <<<(E + 255) / 256, 256, 0, stream>>>(ei, cnt, E);
    k_scan   <<<1, 1024, 0, stream>>>(cnt, offs, cur, dinv, N, E);
    k_reorder<<<(E + 255) / 256, 256, 0, stream>>>(ei, cur, es, E);
    k_gemm   <<<2048, 256, 0, stream>>>(x, W, b, dinv, h, out, N);
    k_gather <<<(N + 3) / 4, 256, 0, stream>>>(offs, es, dinv, h, out, N);
    k_stats  <<<512, 256, 0, stream>>>(out, stats, N);
    k_final  <<<(N * 64 + 255) / 256, 256, 0, stream>>>(out, stats, gamma, beta, N, 1.0f / N);
}

// Round 6
// 249.505 us; speedup vs baseline: 1.5231x; 1.5231x over previous
//
#include <hip/hip_runtime.h>

#define DIM 64
#define BN_EPS 1e-5f
#define L2_EPS 1e-12f

// ---------- build CSR by dst ----------
__global__ __launch_bounds__(256) void k_hist(const int* __restrict__ ei,
                                              int* __restrict__ cnt, int E) {
    int e = blockIdx.x * blockDim.x + threadIdx.x;
    if (e < E) atomicAdd(&cnt[ei[E + e]], 1);
}

// ---- 3-phase parallel exclusive scan over cnt (1024 elems per block) ----
__global__ __launch_bounds__(256) void k_blocksum(const int* __restrict__ cnt,
                                                  int* __restrict__ partials, int N) {
    int t = threadIdx.x;
    int base = blockIdx.x * 1024 + t * 4;
    int s = 0;
    if (base + 3 < N) {
        int4 v = *(const int4*)(cnt + base);
        s = v.x + v.y + v.z + v.w;
    } else {
#pragma unroll
        for (int i = 0; i < 4; ++i) if (base + i < N) s += cnt[base + i];
    }
    __shared__ int ls[256];
    ls[t] = s;
    __syncthreads();
    for (int off = 128; off; off >>= 1) {
        if (t < off) ls[t] += ls[t + off];
        __syncthreads();
    }
    if (t == 0) partials[blockIdx.x] = ls[0];
}

__global__ __launch_bounds__(1024) void k_scanpartials(int* __restrict__ partials, int B) {
    __shared__ int buf[1024];
    int t = threadIdx.x;
    int v = (t < B) ? partials[t] : 0;
    buf[t] = v;
    __syncthreads();
    for (int off = 1; off < 1024; off <<= 1) {
        int u = (t >= off) ? buf[t - off] : 0;
        __syncthreads();
        buf[t] += u;
        __syncthreads();
    }
    if (t < B) partials[t] = buf[t] - v;   // exclusive
}

__global__ __launch_bounds__(256) void k_applyscan(const int* __restrict__ cnt,
                                                   const int* __restrict__ partials,
                                                   int* __restrict__ offs,
                                                   int* __restrict__ cur,
                                                   float* __restrict__ dinv,
                                                   int N, int E) {
    int t = threadIdx.x;
    int base = blockIdx.x * 1024 + t * 4;
    int c0 = 0, c1 = 0, c2 = 0, c3 = 0;
    if (base + 3 < N) {
        int4 v = *(const int4*)(cnt + base);
        c0 = v.x; c1 = v.y; c2 = v.z; c3 = v.w;
    } else {
        if (base + 0 < N) c0 = cnt[base + 0];
        if (base + 1 < N) c1 = cnt[base + 1];
        if (base + 2 < N) c2 = cnt[base + 2];
        if (base + 3 < N) c3 = cnt[base + 3];
    }
    int T = c0 + c1 + c2 + c3;
    __shared__ int ls[256];
    ls[t] = T;
    __syncthreads();
    for (int off = 1; off < 256; off <<= 1) {   // Hillis-Steele inclusive
        int u = (t >= off) ? ls[t - off] : 0;
        __syncthreads();
        ls[t] += u;
        __syncthreads();
    }
    int o0 = ls[t] - T + partials[blockIdx.x];
    int o1 = o0 + c0, o2 = o1 + c1, o3 = o2 + c2;
    if (base + 0 < N) { offs[base+0]=o0; cur[base+0]=o0; dinv[base+0]=rsqrtf((float)(c0+1)); }
    if (base + 1 < N) { offs[base+1]=o1; cur[base+1]=o1; dinv[base+1]=rsqrtf((float)(c1+1)); }
    if (base + 2 < N) { offs[base+2]=o2; cur[base+2]=o2; dinv[base+2]=rsqrtf((float)(c2+1)); }
    if (base + 3 < N) { offs[base+3]=o3; cur[base+3]=o3; dinv[base+3]=rsqrtf((float)(c3+1)); }
    if (blockIdx.x == 0 && t == 0) offs[N] = E;
}

__global__ __launch_bounds__(256) void k_reorder(const int* __restrict__ ei,
                                                 int* __restrict__ cur,
                                                 int* __restrict__ es, int E) {
    int e = blockIdx.x * blockDim.x + threadIdx.x;
    if (e < E) {
        int s = ei[e];
        int d = ei[E + e];
        int p = atomicAdd(&cur[d], 1);
        es[p] = s;
    }
}

// ---------- h = x @ W ; out = h*dinv^2 + b (self-loop + bias) ----------
__global__ __launch_bounds__(256) void k_gemm(const float* __restrict__ x,
                                              const float* __restrict__ W,
                                              const float* __restrict__ b,
                                              const float* __restrict__ dinv,
                                              float* __restrict__ h,
                                              float* __restrict__ out, int N) {
    __shared__ float Ws[DIM][DIM];
    __shared__ float xs[4][DIM];
    int tid = threadIdx.x;
    for (int i = tid; i < DIM * DIM; i += 256) Ws[i >> 6][i & 63] = W[i];
    __syncthreads();
    int tx = tid & 63, ty = tid >> 6;
    float bj = b[tx];
    for (int r0 = blockIdx.x * 4; r0 < N; r0 += gridDim.x * 4) {
        int r = r0 + ty;
        __syncthreads();
        xs[ty][tx] = x[r * DIM + tx];
        __syncthreads();
        float acc = 0.f;
#pragma unroll
        for (int k = 0; k < DIM; ++k) acc = fmaf(xs[ty][k], Ws[k][tx], acc);
        h[r * DIM + tx] = acc;
        float di = dinv[r];
        out[r * DIM + tx] = acc * di * di + bj;
    }
}

// ---------- gather: one wave per dst row; 4 edges x 16 lanes x float4 ----------
__global__ __launch_bounds__(256) void k_gather(const int* __restrict__ offs,
                                                const int* __restrict__ es,
                                                const float* __restrict__ dinv,
                                                const float* __restrict__ h,
                                                float* __restrict__ out, int N) {
    int w = threadIdx.x >> 6;             // wave in block (0..3)
    int d = blockIdx.x * 4 + w;           // dst node
    if (d >= N) return;
    int l = threadIdx.x & 63;
    int sub = l >> 4;                     // edge slot 0..3
    int c = l & 15;                       // float4 column
    int beg = offs[d], end = offs[d + 1];
    const float4* __restrict__ h4 = (const float4*)h;
    float4 acc = make_float4(0.f, 0.f, 0.f, 0.f);
    for (int base = beg; base < end; base += 4) {
        int k = base + sub;
        bool valid = k < end;
        int idx = valid ? k : beg;
        int s = es[idx];
        float wgt = valid ? dinv[s] : 0.f;
        float4 hv = h4[(size_t)s * 16 + c];
        acc.x = fmaf(wgt, hv.x, acc.x);
        acc.y = fmaf(wgt, hv.y, acc.y);
        acc.z = fmaf(wgt, hv.z, acc.z);
        acc.w = fmaf(wgt, hv.w, acc.w);
    }
    acc.x += __shfl_xor(acc.x, 16, 64); acc.y += __shfl_xor(acc.y, 16, 64);
    acc.z += __shfl_xor(acc.z, 16, 64); acc.w += __shfl_xor(acc.w, 16, 64);
    acc.x += __shfl_xor(acc.x, 32, 64); acc.y += __shfl_xor(acc.y, 32, 64);
    acc.z += __shfl_xor(acc.z, 32, 64); acc.w += __shfl_xor(acc.w, 32, 64);
    if (sub == 0) {
        float dd = dinv[d];
        float4* out4 = (float4*)out;
        float4 o = out4[(size_t)d * 16 + c];
        o.x = fmaf(dd, acc.x, o.x);
        o.y = fmaf(dd, acc.y, o.y);
        o.z = fmaf(dd, acc.z, o.z);
        o.w = fmaf(dd, acc.w, o.w);
        out4[(size_t)d * 16 + c] = o;
    }
}

// ---------- column stats ----------
__global__ __launch_bounds__(256) void k_stats(const float* __restrict__ out,
                                               float* __restrict__ stats, int N) {
    int tx = threadIdx.x & 63, ty = threadIdx.x >> 6;
    float s = 0.f, q = 0.f;
    for (int r = blockIdx.x * 4 + ty; r < N; r += gridDim.x * 4) {
        float v = out[r * DIM + tx];
        s += v;
        q = fmaf(v, v, q);
    }
    __shared__ float ls[4][DIM], lq[4][DIM];
    ls[ty][tx] = s;
    lq[ty][tx] = q;
    __syncthreads();
    if (ty == 0) {
        s = ls[0][tx] + ls[1][tx] + ls[2][tx] + ls[3][tx];
        q = lq[0][tx] + lq[1][tx] + lq[2][tx] + lq[3][tx];
        atomicAdd(&stats[tx], s);
        atomicAdd(&stats[DIM + tx], q);
    }
}

// ---------- BN -> ReLU -> row L2 normalize ----------
__global__ __launch_bounds__(256) void k_final(float* __restrict__ out,
                                               const float* __restrict__ stats,
                                               const float* __restrict__ gamma,
                                               const float* __restrict__ beta,
                                               int N, float invN) {
    int tx = threadIdx.x & 63;
    int r = (blockIdx.x * blockDim.x + threadIdx.x) >> 6;
    if (r >= N) return;
    float mean = stats[tx] * invN;
    float var = fmaf(-mean, mean, stats[DIM + tx] * invN);
    float rstd = rsqrtf(var + BN_EPS);
    float v = out[r * DIM + tx];
    v = (v - mean) * rstd * gamma[tx] + beta[tx];
    v = fmaxf(v, 0.f);
    float q = v * v;
#pragma unroll
    for (int off = 32; off; off >>= 1) q += __shfl_xor(q, off, 64);
    float nrm = sqrtf(q);
    out[r * DIM + tx] = v / fmaxf(nrm, L2_EPS);
}

extern "C" void kernel_launch(void* const* d_in, const int* in_sizes, int n_in,
                              void* d_out, int out_size, void* d_ws, size_t ws_size,
                              hipStream_t stream) {
    const float* x     = (const float*)d_in[0];
    const int*   ei    = (const int*)d_in[1];
    const float* W     = (const float*)d_in[2];
    const float* b     = (const float*)d_in[3];
    const float* gamma = (const float*)d_in[4];
    const float* beta  = (const float*)d_in[5];
    float* out = (float*)d_out;

    const int N = in_sizes[0] / DIM;      // 50000
    const int E = in_sizes[1] / 2;        // 800000
    const int B = (N + 1023) / 1024;      // scan blocks (49)

    // workspace layout (element offsets, padded to 256-elem boundaries)
    float* wsf = (float*)d_ws;
    const int STATS_OFF = 0;                                   // 128 f
    const int CNT_OFF   = 256;                                 // N int
    const int OFFS_OFF  = CNT_OFF  + ((N + 256) & ~255);       // N+1 int
    const int CUR_OFF   = OFFS_OFF + ((N + 256) & ~255);       // N int
    const int DINV_OFF  = CUR_OFF  + ((N + 256) & ~255);       // N f
    const int PART_OFF  = DINV_OFF + ((N + 256) & ~255);       // B int (<=1024)
    const int H_OFF     = PART_OFF + 1024;                     // N*64 f (16B aligned)
    const int ES_OFF    = H_OFF + N * DIM;                     // E int

    float* stats = wsf + STATS_OFF;
    int*   cnt   = (int*)(wsf + CNT_OFF);
    int*   offs  = (int*)(wsf + OFFS_OFF);
    int*   cur   = (int*)(wsf + CUR_OFF);
    float* dinv  = wsf + DINV_OFF;
    int*   part  = (int*)(wsf + PART_OFF);
    float* h     = wsf + H_OFF;
    int*   es    = (int*)(wsf + ES_OFF);

    // zero stats + cnt in one shot (contiguous region)
    hipMemsetAsync(wsf, 0, (size_t)(CNT_OFF + N) * sizeof(float), stream);

    k_hist        <<<(E + 255) / 256, 256, 0, stream>>>(ei, cnt, E);
    k_blocksum    <<<B, 256, 0, stream>>>(cnt, part, N);
    k_scanpartials<<<1, 1024, 0, stream>>>(part, B);
    k_applyscan   <<<B, 256, 0, stream>>>(cnt, part, offs, cur, dinv, N, E);
    k_reorder     <<<(E + 255) / 256, 256, 0, stream>>>(ei, cur, es, E);
    k_gemm        <<<2048, 256, 0, stream>>>(x, W, b, dinv, h, out, N);
    k_gather      <<<(N + 3) / 4, 256, 0, stream>>>(offs, es, dinv, h, out, N);
    k_stats       <<<512, 256, 0, stream>>>(out, stats, N);
    k_final       <<<(N * 64 + 255) / 256, 256, 0, stream>>>(out, stats, gamma, beta, N, 1.0f / N);
}